// Round 3
// baseline (209.064 us; speedup 1.0000x reference)
//
#include <hip/hip_runtime.h>

typedef short bf16x8 __attribute__((ext_vector_type(8)));
typedef float f32x4 __attribute__((ext_vector_type(4)));
typedef unsigned long long u64x2 __attribute__((ext_vector_type(2)));
typedef unsigned short u16;

// ---------- helpers ----------

__device__ __forceinline__ u16 f2b(float f) {
  unsigned int u = __float_as_uint(f);
  u += 0x7fffu + ((u >> 16) & 1u);   // RNE
  return (u16)(u >> 16);
}

__device__ __forceinline__ void gload16(const void* g, void* l) {
  __builtin_amdgcn_global_load_lds(
      (const __attribute__((address_space(1))) void*)g,
      (__attribute__((address_space(3))) void*)l, 16, 0, 0);
}

#define SBAR() __builtin_amdgcn_sched_barrier(0)
#define BAR()  do { SBAR(); __builtin_amdgcn_s_barrier(); SBAR(); } while (0)
#define LGKM0() do { asm volatile("s_waitcnt lgkmcnt(0)" ::: "memory"); SBAR(); } while (0)
#define VM0()  do { asm volatile("s_waitcnt vmcnt(0)" ::: "memory"); SBAR(); } while (0)

// ---------- 256x256 BK=64 8-wave NT GEMM, 8-phase schedule (m201 port) ----
// A: rows [i0,i0+256) x K row-major lda; B: rows [j0,j0+256) x K row-major ldb.
// D[m][n] = sum_k A[i0+m][k]*B[j0+n][k], k in [0, nk*64).
// 512 thr = 8 waves (2M x 4N); per-wave C 128x64 = acc[8][4].
// LDS 128 KiB: 2 dbuf x (A 256x64 + B 256x64) bf16, XOR-swizzled slots.

__device__ __forceinline__ void stage_tile(
    const u16* __restrict__ gA, int lda, const u16* __restrict__ gB, int ldb,
    u16* bufA, u16* bufB)
{
  const int t = threadIdx.x;
  const int rb = t >> 3;                        // row 0..63 (+64/round)
  const int c16 = ((t & 7) ^ (rb & 7)) * 8;     // swizzled 16B slot (elems)
  const u16* pa = gA + (size_t)rb * lda + c16;
  const u16* pb = gB + (size_t)rb * ldb + c16;
  char* da = (char*)bufA + t * 16;
  char* db = (char*)bufB + t * 16;
#pragma unroll
  for (int rnd = 0; rnd < 4; ++rnd) {
    gload16(pa + (size_t)(rnd * 64) * lda, da + rnd * 8192);
    gload16(pb + (size_t)(rnd * 64) * ldb, db + rnd * 8192);
  }
}

__device__ __forceinline__ void read_a_frags(
    const u16* bufA, int wrow, int mh, int rr, int laneOff, bf16x8 af[2][4])
{
#pragma unroll
  for (int mi = 0; mi < 4; ++mi) {
    const char* base = (const char*)bufA + (wrow * 128 + mh * 64 + mi * 16 + rr) * 128;
    af[0][mi] = *(const bf16x8*)(base + laneOff);
    af[1][mi] = *(const bf16x8*)(base + (laneOff ^ 64));
  }
}

__device__ __forceinline__ void read_b_frags(
    const u16* bufB, int wcol, int nh, int rr, int laneOff, bf16x8 bfr[2][2])
{
#pragma unroll
  for (int ni = 0; ni < 2; ++ni) {
    const char* base = (const char*)bufB + (wcol * 64 + nh * 32 + ni * 16 + rr) * 128;
    bfr[0][ni] = *(const bf16x8*)(base + laneOff);
    bfr[1][ni] = *(const bf16x8*)(base + (laneOff ^ 64));
  }
}

__device__ __forceinline__ void mfma16(
    const bf16x8 af[2][4], const bf16x8 bfr[2][2], f32x4 acc[8][4], int mh, int nh)
{
  __builtin_amdgcn_s_setprio(1);
#pragma unroll
  for (int kh = 0; kh < 2; ++kh)
#pragma unroll
    for (int mi = 0; mi < 4; ++mi)
#pragma unroll
      for (int ni = 0; ni < 2; ++ni)
        acc[mh * 4 + mi][nh * 2 + ni] = __builtin_amdgcn_mfma_f32_16x16x32_bf16(
            af[kh][mi], bfr[kh][ni], acc[mh * 4 + mi][nh * 2 + ni], 0, 0, 0);
  __builtin_amdgcn_s_setprio(0);
}

__device__ __forceinline__ void gemm256(
    const u16* __restrict__ A, int lda, const u16* __restrict__ B, int ldb,
    int i0, int j0, int nk, u16* lds, f32x4 acc[8][4])
{
  u16* bufA0 = lds;
  u16* bufB0 = lds + 16384;
  u16* bufA1 = lds + 32768;
  u16* bufB1 = lds + 49152;
  const int t = threadIdx.x;
  const int lane = t & 63, wid = t >> 6;
  const int wrow = wid >> 2, wcol = wid & 3;
  const int rr = lane & 15, kg = lane >> 4;
  const int laneOff = (kg * 16) ^ ((rr & 7) << 4);
  const u16* Abase = A + (size_t)i0 * lda;
  const u16* Bbase = B + (size_t)j0 * ldb;

  stage_tile(Abase, lda, Bbase, ldb, bufA0, bufB0);
  VM0();
  BAR();

  bf16x8 af[2][4], bf0[2][2], bf1[2][2];
  for (int kt = 0; kt < nk; ++kt) {
    const u16* bA = (kt & 1) ? bufA1 : bufA0;
    const u16* bB = (kt & 1) ? bufB1 : bufB0;
    u16* dA = (kt & 1) ? bufA0 : bufA1;
    u16* dB = (kt & 1) ? bufB0 : bufB1;

    // ---- phase 0: A(mh0) + B(nh0) reads; issue next K-tile prefetch ----
    read_a_frags(bA, wrow, 0, rr, laneOff, af);
    read_b_frags(bB, wcol, 0, rr, laneOff, bf0);
    if (kt + 1 < nk)
      stage_tile(Abase + (size_t)(kt + 1) * 64, lda,
                 Bbase + (size_t)(kt + 1) * 64, ldb, dA, dB);
    BAR();
    LGKM0();
    mfma16(af, bf0, acc, 0, 0);
    BAR();

    // ---- phase 1: B(nh1) reads; A reused from regs ----
    read_b_frags(bB, wcol, 1, rr, laneOff, bf1);
    BAR();
    LGKM0();
    mfma16(af, bf1, acc, 0, 1);
    BAR();

    // ---- phase 2: A(mh1) reads; B(nh0) reused from regs ----
    read_a_frags(bA, wrow, 1, rr, laneOff, af);
    BAR();
    LGKM0();
    mfma16(af, bf0, acc, 1, 0);
    BAR();

    // ---- phase 3: pure MFMA; then publish next K-tile ----
    mfma16(af, bf1, acc, 1, 1);
    VM0();    // prefetch issued ~3 phases ago -> nearly free
    BAR();
  }
}

// ---------- kernel 0: fp32 -> bf16 conversion (x and stacked W) ----------
__global__ __launch_bounds__(256) void k_convert(
    const float* __restrict__ x, const float* __restrict__ Wq,
    const float* __restrict__ Wk, const float* __restrict__ Wv,
    u16* __restrict__ xb, u16* __restrict__ Wb)
{
  const size_t NX = 8388608;
  size_t base = ((size_t)blockIdx.x * 256 + threadIdx.x) * 4;
  float4 v;
  u16* dst;
  if (base < NX) {
    v = *(const float4*)(x + base);
    dst = xb + base;
  } else {
    size_t wb = base - NX;
    int sel = (int)(wb >> 20);
    const float* W = (sel == 0) ? Wq : ((sel == 1) ? Wk : Wv);
    v = *(const float4*)(W + (wb & 1048575));
    dst = Wb + wb;
  }
  dst[0] = f2b(v.x); dst[1] = f2b(v.y); dst[2] = f2b(v.z); dst[3] = f2b(v.w);
}

// ---------- kernel 1: QKV projection ----------
// C[8192][3072] = xb @ Wb^T.  bj 0-3 -> Q, 4-7 -> K' (=k+x+P), 8-11 -> V^T.
__global__ __launch_bounds__(512, 2) void k_qkv(
    const u16* __restrict__ xb, const u16* __restrict__ Wb,
    const float* __restrict__ bq, const float* __restrict__ bk,
    const float* __restrict__ bv, const float* __restrict__ x,
    const float* __restrict__ P,
    u16* __restrict__ Qb, u16* __restrict__ Kpb, u16* __restrict__ Vtb)
{
  extern __shared__ __align__(16) u16 lds[];
  const int bx = blockIdx.x;
  const int bi = bx & 31, bj = bx >> 5;   // 32 M-tiles x 12 N-tiles
  const int i0 = bi * 256, j0 = bj * 256;
  f32x4 acc[8][4];
#pragma unroll
  for (int a = 0; a < 8; ++a)
#pragma unroll
    for (int b = 0; b < 4; ++b) acc[a][b] = (f32x4){0.f, 0.f, 0.f, 0.f};

  gemm256(xb, 1024, Wb, 1024, i0, j0, 16, lds, acc);

  const int t = threadIdx.x, lane = t & 63, wid = t >> 6;
  const int wrow = wid >> 2, wcol = wid & 3;
  const int rr = lane & 15, kg = lane >> 4;
  const int sec = j0 >> 10;
  if (sec < 2) {
    const float* bias = sec ? bk : bq;
#pragma unroll
    for (int mi = 0; mi < 8; ++mi)
#pragma unroll
      for (int ni = 0; ni < 4; ++ni)
#pragma unroll
        for (int r = 0; r < 4; ++r) {
          int m = i0 + wrow * 128 + mi * 16 + kg * 4 + r;
          int n = j0 + wcol * 64 + ni * 16 + rr;
          int d = n & 1023;
          float v = acc[mi][ni][r] + bias[d];
          if (sec == 1) {
            int s = m & 2047;
            v += x[(size_t)m * 1024 + d] + P[(size_t)s * 1024 + d];
            Kpb[(size_t)m * 1024 + d] = f2b(v);
          } else {
            Qb[(size_t)m * 1024 + d] = f2b(v);
          }
        }
  } else {
    // V: transpose through (swizzled) LDS, then coalesced 16B stores
    u16* lt = lds;   // 256 x 256 bf16: lt[d_local][s_local ^ swz]
#pragma unroll
    for (int mi = 0; mi < 8; ++mi)
#pragma unroll
      for (int ni = 0; ni < 4; ++ni) {
        int cl = wcol * 64 + ni * 16 + rr;           // d_local
        int d = (j0 & 1023) + cl;
        float bvd = bv[d];
#pragma unroll
        for (int r = 0; r < 4; ++r) {
          int rl = wrow * 128 + mi * 16 + kg * 4 + r; // s_local
          lt[cl * 256 + (rl ^ ((cl & 7) << 3))] = f2b(acc[mi][ni][r] + bvd);
        }
      }
    __syncthreads();
    int b = i0 >> 11, s0 = i0 & 2047, d0 = j0 & 1023;
#pragma unroll
    for (int rnd = 0; rnd < 16; ++rnd) {
      int c = rnd * 512 + t;                  // 8192 x 16B chunks
      int drow = c >> 5, c16 = c & 31;
      int src = drow * 256 + ((c16 * 8) ^ ((drow & 7) << 3));
      *(u64x2*)(&Vtb[((size_t)b * 1024 + d0 + drow) * 2048 + s0 + c16 * 8]) =
          *(const u64x2*)(&lt[src]);
    }
  }
}

// ---------- kernel 2: scores (lower-triangular 256-tiles) ----------
__global__ __launch_bounds__(512, 2) void k_scores(
    const u16* __restrict__ Qb, const u16* __restrict__ Kpb,
    float* __restrict__ Sf)
{
  extern __shared__ __align__(16) u16 lds[];
  const int bx = blockIdx.x;
  const int b = bx / 36;
  const int tt = bx - b * 36;
  int bi = 0;
  while ((bi + 1) * (bi + 2) / 2 <= tt) ++bi;
  const int bj = tt - bi * (bi + 1) / 2;
  const int i0 = bi * 256, j0 = bj * 256;
  const u16* A = Qb + (size_t)b * 2048 * 1024;
  const u16* B = Kpb + (size_t)b * 2048 * 1024;

  f32x4 acc[8][4];
#pragma unroll
  for (int a = 0; a < 8; ++a)
#pragma unroll
    for (int c = 0; c < 4; ++c) acc[a][c] = (f32x4){0.f, 0.f, 0.f, 0.f};

  gemm256(A, 1024, B, 1024, i0, j0, 16, lds, acc);

  const int t = threadIdx.x, lane = t & 63, wid = t >> 6;
  const int wrow = wid >> 2, wcol = wid & 3;
  const int rr = lane & 15, kg = lane >> 4;
  float* Sb = Sf + (size_t)b * 2048 * 2048;
#pragma unroll
  for (int mi = 0; mi < 8; ++mi)
#pragma unroll
    for (int ni = 0; ni < 4; ++ni)
#pragma unroll
      for (int r = 0; r < 4; ++r) {
        int m = i0 + wrow * 128 + mi * 16 + kg * 4 + r;
        int n = j0 + wcol * 64 + ni * 16 + rr;
        Sb[(size_t)m * 2048 + n] = acc[mi][ni][r] * 0.03125f;
      }
}

// ---------- kernel 3: row softmax (causal), register-cached ----------
__global__ __launch_bounds__(256) void k_softmax(
    const float* __restrict__ Sf, u16* __restrict__ Pb)
{
  __shared__ float red[4];
  const int row = blockIdx.x;          // b*2048 + i
  const int i = row & 2047;
  const int L = i + 1;
  const int Jend = ((i >> 8) + 1) << 8;   // causal tile boundary for PV
  const float* s = Sf + (size_t)row * 2048;
  u16* p = Pb + (size_t)row * 2048;
  const int t = threadIdx.x;

  float vals[8];
  float m = -3.0e38f;
#pragma unroll
  for (int u = 0; u < 8; ++u) {
    int j = t + u * 256;
    if (j < L) { vals[u] = s[j]; m = fmaxf(m, vals[u]); }
  }
#pragma unroll
  for (int off = 32; off >= 1; off >>= 1) m = fmaxf(m, __shfl_down(m, off, 64));
  if ((t & 63) == 0) red[t >> 6] = m;
  __syncthreads();
  m = fmaxf(fmaxf(red[0], red[1]), fmaxf(red[2], red[3]));
  __syncthreads();

  float sum = 0.f;
#pragma unroll
  for (int u = 0; u < 8; ++u) {
    int j = t + u * 256;
    if (j < L) { vals[u] = __expf(vals[u] - m); sum += vals[u]; }
  }
#pragma unroll
  for (int off = 32; off >= 1; off >>= 1) sum += __shfl_down(sum, off, 64);
  if ((t & 63) == 0) red[t >> 6] = sum;
  __syncthreads();
  const float inv = 1.f / (red[0] + red[1] + red[2] + red[3]);

#pragma unroll
  for (int u = 0; u < 8; ++u) {
    int j = t + u * 256;
    if (j < Jend) p[j] = (j < L) ? f2b(vals[u] * inv) : (u16)0;
  }
}

// ---------- kernel 4: out = P @ V (pre-transposed Vtb) ----------
__global__ __launch_bounds__(512, 2) void k_pv(
    const u16* __restrict__ Pb, const u16* __restrict__ Vtb,
    float* __restrict__ out)
{
  extern __shared__ __align__(16) u16 lds[];
  const int bx = blockIdx.x;
  const int b = bx >> 5;
  const int bi = (bx >> 2) & 7;
  const int bj = bx & 3;
  const int i0 = bi * 256, j0 = bj * 256;
  const u16* A = Pb + (size_t)b * 2048 * 2048;   // lda 2048
  const u16* B = Vtb + (size_t)b * 1024 * 2048;  // ldb 2048

  f32x4 acc[8][4];
#pragma unroll
  for (int a = 0; a < 8; ++a)
#pragma unroll
    for (int c = 0; c < 4; ++c) acc[a][c] = (f32x4){0.f, 0.f, 0.f, 0.f};

  // causal: probs zero for j >= (bi+1)*256 -> only 4*(bi+1) K-tiles of 64
  gemm256(A, 2048, B, 2048, i0, j0, 4 * (bi + 1), lds, acc);

  const int t = threadIdx.x, lane = t & 63, wid = t >> 6;
  const int wrow = wid >> 2, wcol = wid & 3;
  const int rr = lane & 15, kg = lane >> 4;
  float* ob = out + (size_t)b * 2048 * 1024;
#pragma unroll
  for (int mi = 0; mi < 8; ++mi)
#pragma unroll
    for (int ni = 0; ni < 4; ++ni)
#pragma unroll
      for (int r = 0; r < 4; ++r) {
        int m = i0 + wrow * 128 + mi * 16 + kg * 4 + r;
        int n = j0 + wcol * 64 + ni * 16 + rr;
        ob[(size_t)m * 1024 + n] = acc[mi][ni][r];
      }
}

// ---------- launch ----------
extern "C" void kernel_launch(void* const* d_in, const int* in_sizes, int n_in,
                              void* d_out, int out_size, void* d_ws, size_t ws_size,
                              hipStream_t stream) {
  const float* x  = (const float*)d_in[0];
  const float* Wq = (const float*)d_in[1];
  const float* bq = (const float*)d_in[2];
  const float* Wk = (const float*)d_in[3];
  const float* bk = (const float*)d_in[4];
  const float* Wv = (const float*)d_in[5];
  const float* bv = (const float*)d_in[6];
  const float* P  = (const float*)d_in[7];
  float* out = (float*)d_out;

  char* w = (char*)d_ws;
  u16*  xb  = (u16*)(w);                   // 16 MB
  u16*  Wb  = (u16*)(w + (16ull << 20));   //  6 MB
  u16*  Qb  = (u16*)(w + (22ull << 20));   // 16 MB
  u16*  Kpb = (u16*)(w + (38ull << 20));   // 16 MB
  u16*  Vtb = (u16*)(w + (54ull << 20));   // 16 MB
  float* Sf = (float*)(w + (70ull << 20)); // 64 MB
  u16*  Pb  = (u16*)(w + (134ull << 20));  // 32 MB

  const int LDSB = 131072;
  (void)hipFuncSetAttribute((const void*)k_qkv,
        hipFuncAttributeMaxDynamicSharedMemorySize, LDSB);
  (void)hipFuncSetAttribute((const void*)k_scores,
        hipFuncAttributeMaxDynamicSharedMemorySize, LDSB);
  (void)hipFuncSetAttribute((const void*)k_pv,
        hipFuncAttributeMaxDynamicSharedMemorySize, LDSB);

  hipLaunchKernelGGL(k_convert, dim3(11264), dim3(256), 0, stream,
                     x, Wq, Wk, Wv, xb, Wb);
  hipLaunchKernelGGL(k_qkv, dim3(384), dim3(512), LDSB, stream,
                     xb, Wb, bq, bk, bv, x, P, Qb, Kpb, Vtb);
  hipLaunchKernelGGL(k_scores, dim3(144), dim3(512), LDSB, stream,
                     Qb, Kpb, Sf);
  hipLaunchKernelGGL(k_softmax, dim3(8192), dim3(256), 0, stream,
                     Sf, Pb);
  hipLaunchKernelGGL(k_pv, dim3(128), dim3(512), LDSB, stream,
                     Pb, Vtb, out);
}

// Round 4
// 186.964 us; speedup vs baseline: 1.1182x; 1.1182x over previous
//
#include <hip/hip_runtime.h>

typedef short bf16x8 __attribute__((ext_vector_type(8)));
typedef float f32x4 __attribute__((ext_vector_type(4)));
typedef unsigned long long u64x2 __attribute__((ext_vector_type(2)));
typedef unsigned short u16;

// ---------- helpers ----------

__device__ __forceinline__ u16 f2b(float f) {
  unsigned int u = __float_as_uint(f);
  u += 0x7fffu + ((u >> 16) & 1u);   // RNE
  return (u16)(u >> 16);
}
__device__ __forceinline__ float b2f(u16 h) {
  return __uint_as_float((unsigned int)h << 16);
}

__device__ __forceinline__ void gload16(const void* g, void* l) {
  __builtin_amdgcn_global_load_lds(
      (const __attribute__((address_space(1))) void*)g,
      (__attribute__((address_space(3))) void*)l, 16, 0, 0);
}

#define SBAR() __builtin_amdgcn_sched_barrier(0)
#define BAR()  do { SBAR(); __builtin_amdgcn_s_barrier(); SBAR(); } while (0)

// ---------- 128x128 BK=32 4-wave NT GEMM, double-buffered, counted vmcnt ----
// A: rows [i0,i0+128) x K row-major lda; B: rows [j0,j0+128) x K row-major ldb.
// D[m][n] = sum_k A[i0+m][k]*B[j0+n][k], k in [0, nk*32).
// 256 thr = 4 waves (2M x 2N); per-wave C 64x64 = acc[4][4].
// LDS 32 KiB: 2 dbuf x (A 128x32 + B 128x32) bf16. Swizzle: 16B slot ^= row&3,
// applied on the GLOBAL source (linear gload_lds dest) and on ds_read addr.

__device__ __forceinline__ void stage32(
    const u16* __restrict__ gA, int lda, const u16* __restrict__ gB, int ldb,
    u16* bufA, u16* bufB)
{
  const int t = threadIdx.x;
  const int r0 = t >> 2;                       // row 0..63 (+64 for chunk 2)
  const int cs = (((t & 3) ^ (r0 & 3)) * 8);   // inverse-swizzled source col
  char* da = (char*)bufA + t * 16;
  char* db = (char*)bufB + t * 16;
  gload16(gA + (size_t)r0 * lda + cs, da);
  gload16(gA + (size_t)(r0 + 64) * lda + cs, da + 4096);
  gload16(gB + (size_t)r0 * ldb + cs, db);
  gload16(gB + (size_t)(r0 + 64) * ldb + cs, db + 4096);
}

__device__ __forceinline__ void gemm128(
    const u16* __restrict__ A, int lda, const u16* __restrict__ B, int ldb,
    int i0, int j0, int nk, u16* lds, f32x4 acc[4][4])
{
  u16* bA0 = lds;
  u16* bB0 = lds + 4096;
  u16* bA1 = lds + 8192;
  u16* bB1 = lds + 12288;
  const int t = threadIdx.x, lane = t & 63, wid = t >> 6;
  const int wrow = wid >> 1, wcol = wid & 1;
  const int rr = lane & 15, kg = lane >> 4;
  const int off = ((kg ^ (rr & 3)) << 4);      // swizzled byte slot
  const u16* Ab = A + (size_t)i0 * lda;
  const u16* Bb = B + (size_t)j0 * ldb;

  stage32(Ab, lda, Bb, ldb, bA0, bB0);
  for (int kt = 0; kt < nk; ++kt) {
    if (kt + 1 < nk) {
      stage32(Ab + (size_t)(kt + 1) * 32, lda, Bb + (size_t)(kt + 1) * 32, ldb,
              (kt & 1) ? bA0 : bA1, (kt & 1) ? bB0 : bB1);
      asm volatile("s_waitcnt vmcnt(4)" ::: "memory");  // tile kt landed
    } else {
      asm volatile("s_waitcnt vmcnt(0)" ::: "memory");
    }
    BAR();                                     // publish buf[kt&1]
    const u16* cA = (kt & 1) ? bA1 : bA0;
    const u16* cB = (kt & 1) ? bB1 : bB0;
    bf16x8 af[4], bf[4];
#pragma unroll
    for (int mi = 0; mi < 4; ++mi)
      af[mi] = *(const bf16x8*)((const char*)cA + (wrow * 64 + mi * 16 + rr) * 64 + off);
#pragma unroll
    for (int ni = 0; ni < 4; ++ni)
      bf[ni] = *(const bf16x8*)((const char*)cB + (wcol * 64 + ni * 16 + rr) * 64 + off);
    __builtin_amdgcn_s_setprio(1);
#pragma unroll
    for (int mi = 0; mi < 4; ++mi)
#pragma unroll
      for (int ni = 0; ni < 4; ++ni)
        acc[mi][ni] = __builtin_amdgcn_mfma_f32_16x16x32_bf16(
            af[mi], bf[ni], acc[mi][ni], 0, 0, 0);
    __builtin_amdgcn_s_setprio(0);
    BAR();                                     // reads of buf[kt&1] done
  }
}

// ---------- kernel 0: fp32 -> bf16 conversion (x, stacked W (+I on Wk), P) --
__global__ __launch_bounds__(256) void k_convert(
    const float* __restrict__ x, const float* __restrict__ Wq,
    const float* __restrict__ Wk, const float* __restrict__ Wv,
    const float* __restrict__ P,
    u16* __restrict__ xb, u16* __restrict__ Wb, u16* __restrict__ Ptab)
{
  const size_t NX = 8388608, NW = 3145728;
  size_t base = ((size_t)blockIdx.x * 256 + threadIdx.x) * 4;
  if (base < NX) {
    float4 v = *(const float4*)(x + base);
    u16* dst = xb + base;
    dst[0] = f2b(v.x); dst[1] = f2b(v.y); dst[2] = f2b(v.z); dst[3] = f2b(v.w);
  } else if (base < NX + NW) {
    size_t wb = base - NX;
    int sel = (int)(wb >> 20);
    const float* W = (sel == 0) ? Wq : ((sel == 1) ? Wk : Wv);
    size_t within = wb & 1048575;
    float4 v = *(const float4*)(W + within);
    if (sel == 1) {            // Wk + I  (folds the +x of pos into the GEMM)
      int row = (int)(within >> 10), c0 = (int)(within & 1023);
      if (row >= c0 && row < c0 + 4) ((float*)&v)[row - c0] += 1.0f;
    }
    u16* dst = Wb + wb;
    dst[0] = f2b(v.x); dst[1] = f2b(v.y); dst[2] = f2b(v.z); dst[3] = f2b(v.w);
  } else {
    size_t pi = base - NX - NW;
    float4 v = *(const float4*)(P + pi);
    u16* dst = Ptab + pi;
    dst[0] = f2b(v.x); dst[1] = f2b(v.y); dst[2] = f2b(v.z); dst[3] = f2b(v.w);
  }
}

// ---------- kernel 1: QKV projection ----------
// C[8192][3072] = xb @ Wb^T. bj 0-7 -> Q, 8-15 -> K''=k+x (P added later),
// 16-23 -> V^T (transposed through LDS).
__global__ __launch_bounds__(256, 4) void k_qkv(
    const u16* __restrict__ xb, const u16* __restrict__ Wb,
    const float* __restrict__ bq, const float* __restrict__ bk,
    const float* __restrict__ bv,
    u16* __restrict__ Qb, u16* __restrict__ Kpb, u16* __restrict__ Vtb)
{
  __shared__ __align__(16) u16 lds[16384];
  const int bx = blockIdx.x;
  const int bi = bx & 63, bj = bx >> 6;   // 64 M-tiles x 24 N-tiles
  const int i0 = bi * 128, j0 = bj * 128;
  f32x4 acc[4][4];
#pragma unroll
  for (int a = 0; a < 4; ++a)
#pragma unroll
    for (int b = 0; b < 4; ++b) acc[a][b] = (f32x4){0.f, 0.f, 0.f, 0.f};

  gemm128(xb, 1024, Wb, 1024, i0, j0, 32, lds, acc);

  const int t = threadIdx.x, lane = t & 63, wid = t >> 6;
  const int wrow = wid >> 1, wcol = wid & 1;
  const int rr = lane & 15, kg = lane >> 4;
  const int sec = j0 >> 10;
  if (sec < 2) {
    const float* bias = sec ? bk : bq;
    u16* dst = sec ? Kpb : Qb;
#pragma unroll
    for (int mi = 0; mi < 4; ++mi)
#pragma unroll
      for (int ni = 0; ni < 4; ++ni)
#pragma unroll
        for (int r = 0; r < 4; ++r) {
          int m = i0 + wrow * 64 + mi * 16 + kg * 4 + r;
          int n = j0 + wcol * 64 + ni * 16 + rr;
          int d = n & 1023;
          dst[(size_t)m * 1024 + d] = f2b(acc[mi][ni][r] + bias[d]);
        }
  } else {
    // V: transpose through swizzled LDS, then coalesced 16B stores
    u16* lt = lds;   // 128 x 128 bf16: lt[d_local][s_local ^ swz]
#pragma unroll
    for (int mi = 0; mi < 4; ++mi)
#pragma unroll
      for (int ni = 0; ni < 4; ++ni) {
        int cl = wcol * 64 + ni * 16 + rr;            // d_local
        float bvd = bv[(j0 & 1023) + cl];
#pragma unroll
        for (int r = 0; r < 4; ++r) {
          int rl = wrow * 64 + mi * 16 + kg * 4 + r;  // s_local
          lt[cl * 128 + (rl ^ ((cl & 7) << 3))] = f2b(acc[mi][ni][r] + bvd);
        }
      }
    __syncthreads();
    int b = i0 >> 11, s0 = i0 & 2047, d0 = j0 & 1023;
#pragma unroll
    for (int rnd = 0; rnd < 8; ++rnd) {
      int c = rnd * 256 + t;                  // 2048 x 16B chunks
      int drow = c >> 4, c16 = c & 15;
      int src = drow * 128 + ((c16 * 8) ^ ((drow & 7) << 3));
      *(u64x2*)(&Vtb[((size_t)b * 1024 + d0 + drow) * 2048 + s0 + c16 * 8]) =
          *(const u64x2*)(&lt[src]);
    }
  }
}

// ---------- kernel 1b: Kpb += P (vectorized bf16) ----------
__global__ __launch_bounds__(256) void k_addP(
    u16* __restrict__ Kpb, const u16* __restrict__ Ptab)
{
  size_t f = ((size_t)blockIdx.x * 256 + threadIdx.x) * 8;
  int m = (int)(f >> 10), d = (int)(f & 1023);
  int s = m & 2047;
  bf16x8 a = *(bf16x8*)(Kpb + f);
  bf16x8 p = *(const bf16x8*)(Ptab + (size_t)s * 1024 + d);
  bf16x8 o;
#pragma unroll
  for (int u = 0; u < 8; ++u)
    o[u] = f2b(b2f((u16)a[u]) + b2f((u16)p[u]));
  *(bf16x8*)(Kpb + f) = o;
}

// ---------- kernel 2: scores (lower-triangular 128-tiles), bf16 out ------
__global__ __launch_bounds__(256, 4) void k_scores(
    const u16* __restrict__ Qb, const u16* __restrict__ Kpb,
    u16* __restrict__ Sb16)
{
  __shared__ __align__(16) u16 lds[16384];
  const int bx = blockIdx.x;
  const int b = bx / 136;
  const int tt = bx - b * 136;
  int bi = 0;
  while ((bi + 1) * (bi + 2) / 2 <= tt) ++bi;
  const int bj = tt - bi * (bi + 1) / 2;
  const int i0 = bi * 128, j0 = bj * 128;
  const u16* A = Qb + (size_t)b * 2048 * 1024;
  const u16* B = Kpb + (size_t)b * 2048 * 1024;

  f32x4 acc[4][4];
#pragma unroll
  for (int a = 0; a < 4; ++a)
#pragma unroll
    for (int c = 0; c < 4; ++c) acc[a][c] = (f32x4){0.f, 0.f, 0.f, 0.f};

  gemm128(A, 1024, B, 1024, i0, j0, 32, lds, acc);

  const int t = threadIdx.x, lane = t & 63, wid = t >> 6;
  const int wrow = wid >> 1, wcol = wid & 1;
  const int rr = lane & 15, kg = lane >> 4;
  u16* Sb = Sb16 + (size_t)b * 2048 * 2048;
#pragma unroll
  for (int mi = 0; mi < 4; ++mi)
#pragma unroll
    for (int ni = 0; ni < 4; ++ni)
#pragma unroll
      for (int r = 0; r < 4; ++r) {
        int m = i0 + wrow * 64 + mi * 16 + kg * 4 + r;
        int n = j0 + wcol * 64 + ni * 16 + rr;
        Sb[(size_t)m * 2048 + n] = f2b(acc[mi][ni][r] * 0.03125f);
      }
}

// ---------- kernel 3: row softmax (causal), 1 bf16x8 chunk per thread ----
__global__ __launch_bounds__(256) void k_softmax(
    const u16* __restrict__ Sb16, u16* __restrict__ Pb)
{
  __shared__ float red[4];
  const int row = blockIdx.x;          // b*2048 + i
  const int i = row & 2047;
  const int L = i + 1;
  const u16* s = Sb16 + (size_t)row * 2048;
  const int t = threadIdx.x;

  bf16x8 ch = *(const bf16x8*)(s + t * 8);
  float vals[8];
  float m = -3.0e38f;
#pragma unroll
  for (int u = 0; u < 8; ++u) {
    int j = t * 8 + u;
    if (j < L) { vals[u] = b2f((u16)ch[u]); m = fmaxf(m, vals[u]); }
  }
#pragma unroll
  for (int off = 32; off >= 1; off >>= 1) m = fmaxf(m, __shfl_down(m, off, 64));
  if ((t & 63) == 0) red[t >> 6] = m;
  __syncthreads();
  m = fmaxf(fmaxf(red[0], red[1]), fmaxf(red[2], red[3]));
  __syncthreads();

  float sum = 0.f;
#pragma unroll
  for (int u = 0; u < 8; ++u) {
    int j = t * 8 + u;
    if (j < L) { vals[u] = __expf(vals[u] - m); sum += vals[u]; }
  }
#pragma unroll
  for (int off = 32; off >= 1; off >>= 1) sum += __shfl_down(sum, off, 64);
  if ((t & 63) == 0) red[t >> 6] = sum;
  __syncthreads();
  const float inv = 1.f / (red[0] + red[1] + red[2] + red[3]);

  bf16x8 ov;
#pragma unroll
  for (int u = 0; u < 8; ++u) {
    int j = t * 8 + u;
    ov[u] = (j < L) ? (short)f2b(vals[u] * inv) : (short)0;
  }
  *(bf16x8*)(Pb + (size_t)row * 2048 + t * 8) = ov;
}

// ---------- kernel 4: out = P @ V (pre-transposed Vtb) ----------
__global__ __launch_bounds__(256, 4) void k_pv(
    const u16* __restrict__ Pb, const u16* __restrict__ Vtb,
    float* __restrict__ out)
{
  __shared__ __align__(16) u16 lds[16384];
  const int bx = blockIdx.x;
  const int b = bx >> 7;
  const int bi = 15 - ((bx >> 3) & 15);   // big tiles first
  const int bj = bx & 7;
  const int i0 = bi * 128, j0 = bj * 128;
  const u16* A = Pb + (size_t)b * 2048 * 2048;   // lda 2048
  const u16* B = Vtb + (size_t)b * 1024 * 2048;  // ldb 2048

  f32x4 acc[4][4];
#pragma unroll
  for (int a = 0; a < 4; ++a)
#pragma unroll
    for (int c = 0; c < 4; ++c) acc[a][c] = (f32x4){0.f, 0.f, 0.f, 0.f};

  // causal: probs zero for j >= (bi+1)*128 -> only (bi+1)*4 K-steps of 32
  gemm128(A, 2048, B, 2048, i0, j0, (bi + 1) * 4, lds, acc);

  const int t = threadIdx.x, lane = t & 63, wid = t >> 6;
  const int wrow = wid >> 1, wcol = wid & 1;
  const int rr = lane & 15, kg = lane >> 4;
  float* ob = out + (size_t)b * 2048 * 1024;
#pragma unroll
  for (int mi = 0; mi < 4; ++mi)
#pragma unroll
    for (int ni = 0; ni < 4; ++ni)
#pragma unroll
      for (int r = 0; r < 4; ++r) {
        int m = i0 + wrow * 64 + mi * 16 + kg * 4 + r;
        int n = j0 + wcol * 64 + ni * 16 + rr;
        ob[(size_t)m * 1024 + n] = acc[mi][ni][r];
      }
}

// ---------- launch ----------
extern "C" void kernel_launch(void* const* d_in, const int* in_sizes, int n_in,
                              void* d_out, int out_size, void* d_ws, size_t ws_size,
                              hipStream_t stream) {
  const float* x  = (const float*)d_in[0];
  const float* Wq = (const float*)d_in[1];
  const float* bq = (const float*)d_in[2];
  const float* Wk = (const float*)d_in[3];
  const float* bk = (const float*)d_in[4];
  const float* Wv = (const float*)d_in[5];
  const float* bv = (const float*)d_in[6];
  const float* P  = (const float*)d_in[7];
  float* out = (float*)d_out;

  char* w = (char*)d_ws;
  u16*  xb   = (u16*)(w);                   // 16 MB
  u16*  Wb   = (u16*)(w + (16ull << 20));   //  6 MB
  u16*  Qb   = (u16*)(w + (22ull << 20));   // 16 MB
  u16*  Kpb  = (u16*)(w + (38ull << 20));   // 16 MB
  u16*  Vtb  = (u16*)(w + (54ull << 20));   // 16 MB
  u16*  Sb16 = (u16*)(w + (70ull << 20));   // 32 MB
  u16*  Pb   = (u16*)(w + (102ull << 20));  // 32 MB
  u16*  Ptab = (u16*)(w + (134ull << 20));  //  4 MB

  hipLaunchKernelGGL(k_convert, dim3(13312), dim3(256), 0, stream,
                     x, Wq, Wk, Wv, P, xb, Wb, Ptab);
  hipLaunchKernelGGL(k_qkv, dim3(1536), dim3(256), 0, stream,
                     xb, Wb, bq, bk, bv, Qb, Kpb, Vtb);
  hipLaunchKernelGGL(k_addP, dim3(4096), dim3(256), 0, stream,
                     Kpb, Ptab);
  hipLaunchKernelGGL(k_scores, dim3(544), dim3(256), 0, stream,
                     Qb, Kpb, Sb16);
  hipLaunchKernelGGL(k_softmax, dim3(8192), dim3(256), 0, stream,
                     Sb16, Pb);
  hipLaunchKernelGGL(k_pv, dim3(512), dim3(256), 0, stream,
                     Pb, Vtb, out);
}

// Round 5
// 177.762 us; speedup vs baseline: 1.1761x; 1.0518x over previous
//
#include <hip/hip_runtime.h>

typedef short bf16x8 __attribute__((ext_vector_type(8)));
typedef float f32x4 __attribute__((ext_vector_type(4)));
typedef unsigned long long u64x2 __attribute__((ext_vector_type(2)));
typedef unsigned short u16;

// ---------- helpers ----------

__device__ __forceinline__ u16 f2b(float f) {
  unsigned int u = __float_as_uint(f);
  u += 0x7fffu + ((u >> 16) & 1u);   // RNE
  return (u16)(u >> 16);
}
__device__ __forceinline__ float b2f(u16 h) {
  return __uint_as_float((unsigned int)h << 16);
}

__device__ __forceinline__ void gload16(const void* g, void* l) {
  __builtin_amdgcn_global_load_lds(
      (const __attribute__((address_space(1))) void*)g,
      (__attribute__((address_space(3))) void*)l, 16, 0, 0);
}

#define SBAR() __builtin_amdgcn_sched_barrier(0)
#define BAR()  do { SBAR(); __builtin_amdgcn_s_barrier(); SBAR(); } while (0)

// ---------- 128x128 BK=32 4-wave NT GEMM, double-buffered, counted vmcnt ----
// A: rows [i0,i0+128) x K row-major lda; B: rows [j0,j0+128) x K row-major ldb.
// D[m][n] = sum_k A[i0+m][k]*B[j0+n][k], k in [0, nk*32).
// 256 thr = 4 waves (2M x 2N); per-wave C 64x64 = acc[4][4].
// LDS 32 KiB: 2 dbuf x (A 128x32 + B 128x32) bf16.
// Swizzle: 16B slot ^= (row>>1)&3  -> for each 16-lane read group the bank
// position (16*(r&1) + 4*(kg^((r>>1)&3))) is 2-to-1 over 16 rows = free 2-way.
// Applied on the GLOBAL source col (linear gload_lds dest) and on ds_read addr.

__device__ __forceinline__ void stage32(
    const u16* __restrict__ gA, int lda, const u16* __restrict__ gB, int ldb,
    u16* bufA, u16* bufB)
{
  const int t = threadIdx.x;
  const int r0 = t >> 2;                            // row 0..63 (+64 chunk 2)
  const int cs = (((t & 3) ^ ((r0 >> 1) & 3)) * 8); // inverse-swizzled src col
  char* da = (char*)bufA + t * 16;
  char* db = (char*)bufB + t * 16;
  gload16(gA + (size_t)r0 * lda + cs, da);
  gload16(gA + (size_t)(r0 + 64) * lda + cs, da + 4096);   // (r0+64)>>1 &3 == r0>>1 &3
  gload16(gB + (size_t)r0 * ldb + cs, db);
  gload16(gB + (size_t)(r0 + 64) * ldb + cs, db + 4096);
}

__device__ __forceinline__ void gemm128(
    const u16* __restrict__ A, int lda, const u16* __restrict__ B, int ldb,
    int i0, int j0, int nk, u16* lds, f32x4 acc[4][4])
{
  u16* bA0 = lds;
  u16* bB0 = lds + 4096;
  u16* bA1 = lds + 8192;
  u16* bB1 = lds + 12288;
  const int t = threadIdx.x, lane = t & 63, wid = t >> 6;
  const int wrow = wid >> 1, wcol = wid & 1;
  const int rr = lane & 15, kg = lane >> 4;
  const int off = ((kg ^ ((rr >> 1) & 3)) << 4);   // swizzled byte slot
  const u16* Ab = A + (size_t)i0 * lda;
  const u16* Bb = B + (size_t)j0 * ldb;

  stage32(Ab, lda, Bb, ldb, bA0, bB0);
  for (int kt = 0; kt < nk; ++kt) {
    if (kt + 1 < nk) {
      stage32(Ab + (size_t)(kt + 1) * 32, lda, Bb + (size_t)(kt + 1) * 32, ldb,
              (kt & 1) ? bA0 : bA1, (kt & 1) ? bB0 : bB1);
      asm volatile("s_waitcnt vmcnt(4)" ::: "memory");  // tile kt landed
    } else {
      asm volatile("s_waitcnt vmcnt(0)" ::: "memory");
    }
    BAR();                                     // publish buf[kt&1]
    const u16* cA = (kt & 1) ? bA1 : bA0;
    const u16* cB = (kt & 1) ? bB1 : bB0;
    bf16x8 af[4], bf[4];
#pragma unroll
    for (int mi = 0; mi < 4; ++mi)
      af[mi] = *(const bf16x8*)((const char*)cA + (wrow * 64 + mi * 16 + rr) * 64 + off);
#pragma unroll
    for (int ni = 0; ni < 4; ++ni)
      bf[ni] = *(const bf16x8*)((const char*)cB + (wcol * 64 + ni * 16 + rr) * 64 + off);
    __builtin_amdgcn_s_setprio(1);
#pragma unroll
    for (int mi = 0; mi < 4; ++mi)
#pragma unroll
      for (int ni = 0; ni < 4; ++ni)
        acc[mi][ni] = __builtin_amdgcn_mfma_f32_16x16x32_bf16(
            af[mi], bf[ni], acc[mi][ni], 0, 0, 0);
    __builtin_amdgcn_s_setprio(0);
    BAR();                                     // reads of buf[kt&1] done
  }
}

// ---------- kernel 0: fp32 -> bf16 conversion (x, stacked W (+I on Wk), P) --
__global__ __launch_bounds__(256) void k_convert(
    const float* __restrict__ x, const float* __restrict__ Wq,
    const float* __restrict__ Wk, const float* __restrict__ Wv,
    const float* __restrict__ P,
    u16* __restrict__ xb, u16* __restrict__ Wb, u16* __restrict__ Ptab)
{
  const size_t NX = 8388608, NW = 3145728;
  size_t base = ((size_t)blockIdx.x * 256 + threadIdx.x) * 4;
  if (base < NX) {
    float4 v = *(const float4*)(x + base);
    u16* dst = xb + base;
    dst[0] = f2b(v.x); dst[1] = f2b(v.y); dst[2] = f2b(v.z); dst[3] = f2b(v.w);
  } else if (base < NX + NW) {
    size_t wb = base - NX;
    int sel = (int)(wb >> 20);
    const float* W = (sel == 0) ? Wq : ((sel == 1) ? Wk : Wv);
    size_t within = wb & 1048575;
    float4 v = *(const float4*)(W + within);
    if (sel == 1) {            // Wk + I  (folds the +x of pos into the GEMM)
      int row = (int)(within >> 10), c0 = (int)(within & 1023);
      if (row >= c0 && row < c0 + 4) ((float*)&v)[row - c0] += 1.0f;
    }
    u16* dst = Wb + wb;
    dst[0] = f2b(v.x); dst[1] = f2b(v.y); dst[2] = f2b(v.z); dst[3] = f2b(v.w);
  } else {
    size_t pi = base - NX - NW;
    float4 v = *(const float4*)(P + pi);
    u16* dst = Ptab + pi;
    dst[0] = f2b(v.x); dst[1] = f2b(v.y); dst[2] = f2b(v.z); dst[3] = f2b(v.w);
  }
}

// ---------- kernel 1: QKV projection ----------
// C[8192][3072] = xb @ Wb^T. bj 0-7 -> Q, 8-15 -> K' = k + x + P (x folded
// into Wk via +I; P added in epilogue from bf16 Ptab), 16-23 -> V^T.
__global__ __launch_bounds__(256, 4) void k_qkv(
    const u16* __restrict__ xb, const u16* __restrict__ Wb,
    const float* __restrict__ bq, const float* __restrict__ bk,
    const float* __restrict__ bv, const u16* __restrict__ Ptab,
    u16* __restrict__ Qb, u16* __restrict__ Kpb, u16* __restrict__ Vtb)
{
  __shared__ __align__(16) u16 lds[16384];
  const int bx = blockIdx.x;
  const int bi = bx & 63, bj = bx >> 6;   // 64 M-tiles x 24 N-tiles
  const int i0 = bi * 128, j0 = bj * 128;
  f32x4 acc[4][4];
#pragma unroll
  for (int a = 0; a < 4; ++a)
#pragma unroll
    for (int b = 0; b < 4; ++b) acc[a][b] = (f32x4){0.f, 0.f, 0.f, 0.f};

  gemm128(xb, 1024, Wb, 1024, i0, j0, 32, lds, acc);

  const int t = threadIdx.x, lane = t & 63, wid = t >> 6;
  const int wrow = wid >> 1, wcol = wid & 1;
  const int rr = lane & 15, kg = lane >> 4;
  const int sec = j0 >> 10;
  if (sec == 0) {
#pragma unroll
    for (int mi = 0; mi < 4; ++mi)
#pragma unroll
      for (int ni = 0; ni < 4; ++ni)
#pragma unroll
        for (int r = 0; r < 4; ++r) {
          int m = i0 + wrow * 64 + mi * 16 + kg * 4 + r;
          int n = j0 + wcol * 64 + ni * 16 + rr;
          int d = n & 1023;
          Qb[(size_t)m * 1024 + d] = f2b(acc[mi][ni][r] + bq[d]);
        }
  } else if (sec == 1) {
#pragma unroll
    for (int mi = 0; mi < 4; ++mi)
#pragma unroll
      for (int ni = 0; ni < 4; ++ni)
#pragma unroll
        for (int r = 0; r < 4; ++r) {
          int m = i0 + wrow * 64 + mi * 16 + kg * 4 + r;
          int n = j0 + wcol * 64 + ni * 16 + rr;
          int d = n & 1023;
          int s = m & 2047;
          float pv = b2f(Ptab[(size_t)s * 1024 + d]);
          Kpb[(size_t)m * 1024 + d] = f2b(acc[mi][ni][r] + bk[d] + pv);
        }
  } else {
    // V: transpose through swizzled LDS, then coalesced 16B stores
    u16* lt = lds;   // 128 x 128 bf16: lt[d_local][s_local ^ swz]
#pragma unroll
    for (int mi = 0; mi < 4; ++mi)
#pragma unroll
      for (int ni = 0; ni < 4; ++ni) {
        int cl = wcol * 64 + ni * 16 + rr;            // d_local
        float bvd = bv[(j0 & 1023) + cl];
#pragma unroll
        for (int r = 0; r < 4; ++r) {
          int rl = wrow * 64 + mi * 16 + kg * 4 + r;  // s_local
          lt[cl * 128 + (rl ^ ((cl & 7) << 3))] = f2b(acc[mi][ni][r] + bvd);
        }
      }
    __syncthreads();
    int b = i0 >> 11, s0 = i0 & 2047, d0 = j0 & 1023;
#pragma unroll
    for (int rnd = 0; rnd < 8; ++rnd) {
      int c = rnd * 256 + t;                  // 2048 x 16B chunks
      int drow = c >> 4, c16 = c & 15;
      int src = drow * 128 + ((c16 * 8) ^ ((drow & 7) << 3));
      *(u64x2*)(&Vtb[((size_t)b * 1024 + d0 + drow) * 2048 + s0 + c16 * 8]) =
          *(const u64x2*)(&lt[src]);
    }
  }
}

// ---------- kernel 2: scores (lower-triangular 128-tiles), bf16 out ------
__global__ __launch_bounds__(256, 4) void k_scores(
    const u16* __restrict__ Qb, const u16* __restrict__ Kpb,
    u16* __restrict__ Sb16)
{
  __shared__ __align__(16) u16 lds[16384];
  const int bx = blockIdx.x;
  const int b = bx / 136;
  const int tt = bx - b * 136;
  int bi = 0;
  while ((bi + 1) * (bi + 2) / 2 <= tt) ++bi;
  const int bj = tt - bi * (bi + 1) / 2;
  const int i0 = bi * 128, j0 = bj * 128;
  const u16* A = Qb + (size_t)b * 2048 * 1024;
  const u16* B = Kpb + (size_t)b * 2048 * 1024;

  f32x4 acc[4][4];
#pragma unroll
  for (int a = 0; a < 4; ++a)
#pragma unroll
    for (int c = 0; c < 4; ++c) acc[a][c] = (f32x4){0.f, 0.f, 0.f, 0.f};

  gemm128(A, 1024, B, 1024, i0, j0, 32, lds, acc);

  const int t = threadIdx.x, lane = t & 63, wid = t >> 6;
  const int wrow = wid >> 1, wcol = wid & 1;
  const int rr = lane & 15, kg = lane >> 4;
  u16* Sb = Sb16 + (size_t)b * 2048 * 2048;
#pragma unroll
  for (int mi = 0; mi < 4; ++mi)
#pragma unroll
    for (int ni = 0; ni < 4; ++ni)
#pragma unroll
      for (int r = 0; r < 4; ++r) {
        int m = i0 + wrow * 64 + mi * 16 + kg * 4 + r;
        int n = j0 + wcol * 64 + ni * 16 + rr;
        Sb[(size_t)m * 2048 + n] = f2b(acc[mi][ni][r] * 0.03125f);
      }
}

// ---------- kernel 3: row softmax (causal), 1 bf16x8 chunk per thread ----
__global__ __launch_bounds__(256) void k_softmax(
    const u16* __restrict__ Sb16, u16* __restrict__ Pb)
{
  __shared__ float red[4];
  const int row = blockIdx.x;          // b*2048 + i
  const int i = row & 2047;
  const int L = i + 1;
  const int Jend = ((i >> 7) + 1) << 7;   // 128-aligned causal boundary (PV tile)
  const u16* s = Sb16 + (size_t)row * 2048;
  const int t = threadIdx.x;
  const int j0 = t * 8;

  float vals[8];
  float m = -3.0e38f;
  if (j0 < L) {
    bf16x8 ch = *(const bf16x8*)(s + j0);
#pragma unroll
    for (int u = 0; u < 8; ++u) {
      if (j0 + u < L) { vals[u] = b2f((u16)ch[u]); m = fmaxf(m, vals[u]); }
    }
  }
#pragma unroll
  for (int off = 32; off >= 1; off >>= 1) m = fmaxf(m, __shfl_down(m, off, 64));
  if ((t & 63) == 0) red[t >> 6] = m;
  __syncthreads();
  m = fmaxf(fmaxf(red[0], red[1]), fmaxf(red[2], red[3]));
  __syncthreads();

  float sum = 0.f;
  if (j0 < L) {
#pragma unroll
    for (int u = 0; u < 8; ++u) {
      if (j0 + u < L) { vals[u] = __expf(vals[u] - m); sum += vals[u]; }
    }
  }
#pragma unroll
  for (int off = 32; off >= 1; off >>= 1) sum += __shfl_down(sum, off, 64);
  if ((t & 63) == 0) red[t >> 6] = sum;
  __syncthreads();
  const float inv = 1.f / (red[0] + red[1] + red[2] + red[3]);

  if (j0 < Jend) {
    bf16x8 ov;
#pragma unroll
    for (int u = 0; u < 8; ++u) {
      int j = j0 + u;
      ov[u] = (j < L) ? (short)f2b(vals[u] * inv) : (short)0;
    }
    *(bf16x8*)(Pb + (size_t)row * 2048 + j0) = ov;
  }
}

// ---------- kernel 4: out = P @ V (pre-transposed Vtb) ----------
__global__ __launch_bounds__(256, 4) void k_pv(
    const u16* __restrict__ Pb, const u16* __restrict__ Vtb,
    float* __restrict__ out)
{
  __shared__ __align__(16) u16 lds[16384];
  const int bx = blockIdx.x;
  const int b = bx >> 7;
  const int bi = 15 - ((bx >> 3) & 15);   // big tiles first
  const int bj = bx & 7;
  const int i0 = bi * 128, j0 = bj * 128;
  const u16* A = Pb + (size_t)b * 2048 * 2048;   // lda 2048
  const u16* B = Vtb + (size_t)b * 1024 * 2048;  // ldb 2048

  f32x4 acc[4][4];
#pragma unroll
  for (int a = 0; a < 4; ++a)
#pragma unroll
    for (int c = 0; c < 4; ++c) acc[a][c] = (f32x4){0.f, 0.f, 0.f, 0.f};

  // causal: probs zero for j >= (bi+1)*128 -> only (bi+1)*4 K-steps of 32
  gemm128(A, 2048, B, 2048, i0, j0, (bi + 1) * 4, lds, acc);

  const int t = threadIdx.x, lane = t & 63, wid = t >> 6;
  const int wrow = wid >> 1, wcol = wid & 1;
  const int rr = lane & 15, kg = lane >> 4;
  float* ob = out + (size_t)b * 2048 * 1024;
#pragma unroll
  for (int mi = 0; mi < 4; ++mi)
#pragma unroll
    for (int ni = 0; ni < 4; ++ni)
#pragma unroll
      for (int r = 0; r < 4; ++r) {
        int m = i0 + wrow * 64 + mi * 16 + kg * 4 + r;
        int n = j0 + wcol * 64 + ni * 16 + rr;
        ob[(size_t)m * 1024 + n] = acc[mi][ni][r];
      }
}

// ---------- launch ----------
extern "C" void kernel_launch(void* const* d_in, const int* in_sizes, int n_in,
                              void* d_out, int out_size, void* d_ws, size_t ws_size,
                              hipStream_t stream) {
  const float* x  = (const float*)d_in[0];
  const float* Wq = (const float*)d_in[1];
  const float* bq = (const float*)d_in[2];
  const float* Wk = (const float*)d_in[3];
  const float* bk = (const float*)d_in[4];
  const float* Wv = (const float*)d_in[5];
  const float* bv = (const float*)d_in[6];
  const float* P  = (const float*)d_in[7];
  float* out = (float*)d_out;

  char* w = (char*)d_ws;
  u16*  xb   = (u16*)(w);                   // 16 MB
  u16*  Wb   = (u16*)(w + (16ull << 20));   //  6 MB
  u16*  Qb   = (u16*)(w + (22ull << 20));   // 16 MB
  u16*  Kpb  = (u16*)(w + (38ull << 20));   // 16 MB
  u16*  Vtb  = (u16*)(w + (54ull << 20));   // 16 MB
  u16*  Sb16 = (u16*)(w + (70ull << 20));   // 32 MB
  u16*  Pb   = (u16*)(w + (102ull << 20));  // 32 MB
  u16*  Ptab = (u16*)(w + (134ull << 20));  //  4 MB

  hipLaunchKernelGGL(k_convert, dim3(13312), dim3(256), 0, stream,
                     x, Wq, Wk, Wv, P, xb, Wb, Ptab);
  hipLaunchKernelGGL(k_qkv, dim3(1536), dim3(256), 0, stream,
                     xb, Wb, bq, bk, bv, Ptab, Qb, Kpb, Vtb);
  hipLaunchKernelGGL(k_scores, dim3(544), dim3(256), 0, stream,
                     Qb, Kpb, Sb16);
  hipLaunchKernelGGL(k_softmax, dim3(8192), dim3(256), 0, stream,
                     Sb16, Pb);
  hipLaunchKernelGGL(k_pv, dim3(512), dim3(256), 0, stream,
                     Pb, Vtb, out);
}